// Round 10
// baseline (408.636 us; speedup 1.0000x reference)
//
#include <hip/hip_runtime.h>

typedef unsigned short ushortb;
typedef __attribute__((ext_vector_type(8))) short short8;    // 8 bf16 = 16B (MFMA A/B frag)
typedef __attribute__((ext_vector_type(4))) float f32x4;     // MFMA C/D frag

__device__ __forceinline__ ushortb f2bb(float f) {
    union { float f; unsigned u; } x; x.f = f;
    unsigned r = x.u + 0x7fffu + ((x.u >> 16) & 1u);   // RNE
    return (ushortb)(r >> 16);
}
__device__ __forceinline__ float bb2f(ushortb u) {
    union { unsigned u; float f; } x; x.u = ((unsigned)u) << 16; return x.f;
}

// async global->LDS DMA, 16B/lane; lds base wave-uniform, lane -> base+lane*16
__device__ __forceinline__ void async_ld16(void* lds, const void* g) {
    __builtin_amdgcn_global_load_lds(
        (const __attribute__((address_space(1))) void*)g,
        (__attribute__((address_space(3))) void*)lds, 16, 0, 0);
}

// ---------------------------------------------------------------------------
#define EP_ST        1   // plain bf16 store
#define EP_RES       2   // + bf16 residual
#define EP_BIAS_RELU 3   // + bias, relu
#define EP_BIAS_RES  4   // + bias + bf16 residual
#define EP_MEGA      8   // N=2048 fused emb+QKV: h0 | Q | K | V(transposed)

// C[M,N] = A[M,K] @ Bt[N,K]^T (+ epilogue). bf16 in, fp32 MFMA accum, bf16 out.
// Block 256 thr (4 waves 2x2), tile 128x128, BK=64, global_load_lds staging,
// XOR-swizzled unpadded LDS: chunk c of row r at slot c ^ ((r^(r>>3))&7).
template <int EP>
__global__ __launch_bounds__(256) void gemm_mfma(
    const ushortb* __restrict__ A, const ushortb* __restrict__ Bt,
    const float* __restrict__ bias, const ushortb* __restrict__ res,
    const ushortb* __restrict__ tab1, const ushortb* __restrict__ tab2,
    ushortb* __restrict__ C, int M, int N, int K)
{
    __shared__ ushortb sA[128][64];   // 16 KB
    __shared__ ushortb sB[128][64];   // 16 KB

    const int tid = threadIdx.x;
    const int wave = tid >> 6, lane = tid & 63;
    const int quad = lane >> 4, l15 = lane & 15;
    const int row0 = blockIdx.x * 128;
    const int col0 = blockIdx.y * 128;
    const int wm = (wave >> 1) * 64, wn = (wave & 1) * 64;
    const int srl = lane >> 3, slot = lane & 7;

    f32x4 acc[4][4];
    #pragma unroll
    for (int i = 0; i < 4; ++i)
        #pragma unroll
        for (int j = 0; j < 4; ++j) acc[i][j] = (f32x4){0.f, 0.f, 0.f, 0.f};

    for (int k0 = 0; k0 < K; k0 += 64) {
        __syncthreads();
        #pragma unroll
        for (int c = 0; c < 4; ++c) {
            int rbase = wave * 32 + c * 8;
            int r = rbase + srl;
            int ka = (slot ^ ((r ^ (r >> 3)) & 7)) * 8;
            async_ld16(&sA[rbase][0], A  + (size_t)(row0 + r) * K + k0 + ka);
            async_ld16(&sB[rbase][0], Bt + (size_t)(col0 + r) * K + k0 + ka);
        }
        __syncthreads();

        #pragma unroll
        for (int kc = 0; kc < 2; ++kc) {
            short8 af[4], bf[4];
            #pragma unroll
            for (int i = 0; i < 4; ++i) {
                int m = wm + i * 16 + l15;
                af[i] = *(const short8*)&sA[m][(((kc * 4 + quad) ^ ((m ^ (m >> 3)) & 7))) * 8];
            }
            #pragma unroll
            for (int j = 0; j < 4; ++j) {
                int n = wn + j * 16 + l15;
                bf[j] = *(const short8*)&sB[n][(((kc * 4 + quad) ^ ((n ^ (n >> 3)) & 7))) * 8];
            }
            #pragma unroll
            for (int i = 0; i < 4; ++i)
                #pragma unroll
                for (int j = 0; j < 4; ++j)
                    acc[i][j] = __builtin_amdgcn_mfma_f32_16x16x32_bf16(af[i], bf[j], acc[i][j], 0, 0, 0);
        }
    }

    if constexpr (EP == EP_MEGA) {
        // layout: C=h0b; Qb=C+M*512; Kb=C+2*M*512; Vt=C+3*M*512 (contiguous units)
        if (col0 < 512) {
            // h0 = acc + (emb_b+pe)[s][col]  (tab1 = peb bf16 [1024][512])
            #pragma unroll
            for (int i = 0; i < 4; ++i)
                #pragma unroll
                for (int r = 0; r < 4; ++r) {
                    int row = row0 + wm + i * 16 + quad * 4 + r;
                    int s = row & 1023;
                    #pragma unroll
                    for (int j = 0; j < 4; ++j) {
                        int col = col0 + wn + j * 16 + l15;
                        C[(size_t)row * 512 + col] =
                            f2bb(acc[i][j][r] + bb2f(tab1[(s << 9) + col]));
                    }
                }
        } else if (col0 < 1536) {
            // Q (cols 512..1023) / K (1024..1535): acc + peqkv[s][col-512]
            int sec = (col0 - 512) >> 9;
            ushortb* dst = C + (size_t)(1 + sec) * M * 512;
            #pragma unroll
            for (int i = 0; i < 4; ++i)
                #pragma unroll
                for (int r = 0; r < 4; ++r) {
                    int row = row0 + wm + i * 16 + quad * 4 + r;
                    int s = row & 1023;
                    #pragma unroll
                    for (int j = 0; j < 4; ++j) {
                        int cn = col0 + wn + j * 16 + l15 - 512;   // 0..1023
                        dst[(size_t)row * 512 + (cn & 511)] =
                            f2bb(acc[i][j][r] + bb2f(tab2[(size_t)s * 1536 + cn]));
                    }
                }
        } else {
            // V: row=b*1024+s, vcol -> Vt[(b*4+h)*128+e][s], + peqkv
            ushortb* Vt = C + (size_t)3 * M * 512;
            int bb_ = row0 >> 10;
            #pragma unroll
            for (int i = 0; i < 4; ++i) {
                int sb = (row0 & 1023) + wm + i * 16 + quad * 4;
                #pragma unroll
                for (int j = 0; j < 4; ++j) {
                    int cn = col0 + wn + j * 16 + l15 - 512;       // 1024..1535
                    int e = cn & 127, hh = (cn - 1024) >> 7;
                    ushort4 v;
                    v.x = f2bb(acc[i][j][0] + bb2f(tab2[(size_t)(sb + 0) * 1536 + cn]));
                    v.y = f2bb(acc[i][j][1] + bb2f(tab2[(size_t)(sb + 1) * 1536 + cn]));
                    v.z = f2bb(acc[i][j][2] + bb2f(tab2[(size_t)(sb + 2) * 1536 + cn]));
                    v.w = f2bb(acc[i][j][3] + bb2f(tab2[(size_t)(sb + 3) * 1536 + cn]));
                    *(ushort4*)&Vt[((size_t)((bb_ * 4 + hh) * 128 + e) << 10) + sb] = v;
                }
            }
        }
        return;
    }

    #pragma unroll
    for (int i = 0; i < 4; ++i) {
        #pragma unroll
        for (int r = 0; r < 4; ++r) {
            int row = row0 + wm + i * 16 + quad * 4 + r;
            #pragma unroll
            for (int j = 0; j < 4; ++j) {
                int col = col0 + wn + j * 16 + l15;
                float v = acc[i][j][r];
                if constexpr (EP == EP_RES) {
                    v += bb2f(res[(size_t)row * N + col]);
                } else if constexpr (EP == EP_BIAS_RELU) {
                    v = fmaxf(v + bias[col], 0.0f);
                } else if constexpr (EP == EP_BIAS_RES) {
                    v += bias[col] + bb2f(res[(size_t)row * N + col]);
                }
                C[(size_t)row * N + col] = f2bb(v);
            }
        }
    }
}

// ---------------------------------------------------------------------------
// Prep: fp32 -> bf16 elementwise (4/thread)
__global__ __launch_bounds__(256) void conv_b(const float* __restrict__ in,
                                              ushortb* __restrict__ out)
{
    size_t i4 = (size_t)blockIdx.x * 256 + threadIdx.x;
    float4 v = *(const float4*)(in + i4 * 4);
    ushort4 o;
    o.x = f2bb(v.x); o.y = f2bb(v.y); o.z = f2bb(v.z); o.w = f2bb(v.w);
    *(ushort4*)(out + i4 * 4) = o;
}

// LDS-tiled transpose-convert: in fp32 [R][C] (+z*R*C) -> out bf16 [C][R] (+z*R*C), *scale.
__global__ __launch_bounds__(256) void tileT(const float* __restrict__ in,
                                             ushortb* __restrict__ out,
                                             int R, int C, float scale)
{
    __shared__ float t[64][65];
    const int tx = threadIdx.x & 63, ty = threadIdx.x >> 6;
    const int c0 = blockIdx.x * 64, r0 = blockIdx.y * 64;
    const size_t zoff = (size_t)blockIdx.z * R * C;
    #pragma unroll
    for (int i = 0; i < 16; ++i) {
        int r = ty + i * 4;
        t[r][tx] = in[zoff + (size_t)(r0 + r) * C + c0 + tx] * scale;
    }
    __syncthreads();
    #pragma unroll
    for (int i = 0; i < 16; ++i) {
        int r = ty + i * 4;
        out[zoff + (size_t)(c0 + r) * R + r0 + tx] = f2bb(t[tx][r]);
    }
}

// peb[s][c] = pos_encoding(s,c) + emb_b[c], bf16 [1024][512]
__global__ __launch_bounds__(256) void peb_kernel(const float* __restrict__ emb_b,
                                                  ushortb* __restrict__ peb)
{
    int idx = blockIdx.x * 256 + threadIdx.x;    // s*512 + c
    int s = idx >> 9, c = idx & 511;
    float div = expf((float)(c & ~1) * (-9.210340371976184f / 512.0f));
    float ang = (float)s * div;
    float v = ((c & 1) ? cosf(ang) : sinf(ang)) + emb_b[c];
    peb[idx] = f2bb(v);
}

// ---------------------------------------------------------------------------
// MFMA flash attention, fixed-max softmax, DMA-staged K/V, XCD-local grid.
// Qb pre-scaled by log2(e)/sqrt(128) so p = exp2(score). Block = 128 q (32/wave).
// sK[32][128]: chunk c of row t at slot c^(t&15). sVt[128][32]: chunk c of row d
// at slot c^(d&3). Both frag-read patterns land 2-way banks (free).
__global__ __launch_bounds__(256) void attn_mfma(
    const ushortb* __restrict__ Qb, const ushortb* __restrict__ Kb,
    const ushortb* __restrict__ Vt, ushortb* __restrict__ O)
{
    __shared__ ushortb sK[32][128];     // 8 KB
    __shared__ ushortb sVt[128][32];    // 8 KB
    __shared__ ushortb sP[4][32][40];   // 10 KB, [wave][q_local][t]

    const int tid = threadIdx.x;
    const int wave = tid >> 6, lane = tid & 63;
    const int quad = lane >> 4, l15 = lane & 15;
    const int bid = blockIdx.x;          // XCD swizzle: same (b,h) -> ids 64 apart
    const int bh = bid & 63, qc = bid >> 6;
    const int b = bh >> 2, h = bh & 3;
    const int q0 = qc * 128 + wave * 32;
    const size_t qk_off = ((size_t)b << 10) * 512 + h * 128;
    const ushortb* Qp = Qb + qk_off;
    const ushortb* Kp = Kb + qk_off;
    const ushortb* Vp = Vt + (((size_t)(b * 4 + h)) << 17);

    short8 qfA[4], qfB[4];   // B-frags: Q[q=l15 | 16+l15][k=quad*8+j]
    {
        const ushortb* qa = Qp + (size_t)(q0 + l15) * 512;
        const ushortb* qb = Qp + (size_t)(q0 + 16 + l15) * 512;
        #pragma unroll
        for (int kc = 0; kc < 4; ++kc) {
            qfA[kc] = *(const short8*)(qa + kc * 32 + quad * 8);
            qfB[kc] = *(const short8*)(qb + kc * 32 + quad * 8);
        }
    }

    f32x4 oA[8], oB[8];
    #pragma unroll
    for (int dt = 0; dt < 8; ++dt) {
        oA[dt] = (f32x4){0.f, 0.f, 0.f, 0.f};
        oB[dt] = (f32x4){0.f, 0.f, 0.f, 0.f};
    }
    float lA = 0.f, lB = 0.f;

    for (int t0 = 0; t0 < 1024; t0 += 32) {
        __syncthreads();
        // DMA staging: per wave 2 segments, each 1KB of sK + 1KB of sVt
        #pragma unroll
        for (int c = 0; c < 2; ++c) {
            int seg = wave * 2 + c;                       // 0..7
            int rk = seg * 4 + (lane >> 4);               // sK row (256B rows)
            int ck = (lane & 15) ^ (rk & 15);
            async_ld16(&sK[seg * 4][0], Kp + (size_t)(t0 + rk) * 512 + ck * 8);
            int dv = seg * 16 + (lane >> 2);              // sVt row (64B rows)
            int cv = (lane & 3) ^ (dv & 3);
            async_ld16(&sVt[seg * 16][0], Vp + ((size_t)dv << 10) + t0 + cv * 8);
        }
        __syncthreads();

        // S^T: D[t][q]; t = quad*4+reg (+0/16), q = l15 (A-group) / 16+l15 (B)
        f32x4 sA0 = {0,0,0,0}, sA1 = {0,0,0,0}, sB0 = {0,0,0,0}, sB1 = {0,0,0,0};
        #pragma unroll
        for (int kc = 0; kc < 4; ++kc) {
            short8 k0f = *(const short8*)&sK[l15][((kc * 4 + quad) ^ l15) * 8];
            short8 k1f = *(const short8*)&sK[16 + l15][((kc * 4 + quad) ^ l15) * 8];
            sA0 = __builtin_amdgcn_mfma_f32_16x16x32_bf16(k0f, qfA[kc], sA0, 0, 0, 0);
            sA1 = __builtin_amdgcn_mfma_f32_16x16x32_bf16(k1f, qfA[kc], sA1, 0, 0, 0);
            sB0 = __builtin_amdgcn_mfma_f32_16x16x32_bf16(k0f, qfB[kc], sB0, 0, 0, 0);
            sB1 = __builtin_amdgcn_mfma_f32_16x16x32_bf16(k1f, qfB[kc], sB1, 0, 0, 0);
        }

        float pA0[4], pA1[4], pB0[4], pB1[4];
        float sumA = 0.f, sumB = 0.f;
        #pragma unroll
        for (int r = 0; r < 4; ++r) {
            pA0[r] = exp2f(sA0[r]); pA1[r] = exp2f(sA1[r]);
            pB0[r] = exp2f(sB0[r]); pB1[r] = exp2f(sB1[r]);
            sumA += pA0[r] + pA1[r];
            sumB += pB0[r] + pB1[r];
        }
        lA += sumA; lB += sumB;

        ushort4 w;
        w.x = f2bb(pA0[0]); w.y = f2bb(pA0[1]); w.z = f2bb(pA0[2]); w.w = f2bb(pA0[3]);
        *(ushort4*)&sP[wave][l15][quad * 4] = w;
        w.x = f2bb(pA1[0]); w.y = f2bb(pA1[1]); w.z = f2bb(pA1[2]); w.w = f2bb(pA1[3]);
        *(ushort4*)&sP[wave][l15][16 + quad * 4] = w;
        w.x = f2bb(pB0[0]); w.y = f2bb(pB0[1]); w.z = f2bb(pB0[2]); w.w = f2bb(pB0[3]);
        *(ushort4*)&sP[wave][16 + l15][quad * 4] = w;
        w.x = f2bb(pB1[0]); w.y = f2bb(pB1[1]); w.z = f2bb(pB1[2]); w.w = f2bb(pB1[3]);
        *(ushort4*)&sP[wave][16 + l15][16 + quad * 4] = w;

        short8 pfA = *(const short8*)&sP[wave][l15][quad * 8];
        short8 pfB = *(const short8*)&sP[wave][16 + l15][quad * 8];

        #pragma unroll
        for (int dt = 0; dt < 8; ++dt) {
            int d = dt * 16 + l15;
            short8 vfrag = *(const short8*)&sVt[d][(quad ^ (d & 3)) * 8];
            oA[dt] = __builtin_amdgcn_mfma_f32_16x16x32_bf16(pfA, vfrag, oA[dt], 0, 0, 0);
            oB[dt] = __builtin_amdgcn_mfma_f32_16x16x32_bf16(pfB, vfrag, oB[dt], 0, 0, 0);
        }
    }

    lA += __shfl_xor(lA, 16); lA += __shfl_xor(lA, 32);
    lB += __shfl_xor(lB, 16); lB += __shfl_xor(lB, 32);

    const size_t obase = (((size_t)(b * 4 + h) << 10) + q0) << 7;
    #pragma unroll
    for (int r = 0; r < 4; ++r) {
        float invA = 1.0f / __shfl(lA, quad * 4 + r);
        float invB = 1.0f / __shfl(lB, quad * 4 + r);
        int qa = quad * 4 + r, qb = 16 + quad * 4 + r;
        #pragma unroll
        for (int dt = 0; dt < 8; ++dt) {
            O[obase + ((size_t)qa << 7) + dt * 16 + l15] = f2bb(oA[dt][r] * invA);
            O[obase + ((size_t)qb << 7) + dt * 16 + l15] = f2bb(oB[dt][r] * invB);
        }
    }
}

// ---------------------------------------------------------------------------
// LayerNorm over 512 features: wave per row, 8 elems/lane, shuffle reduce.
__global__ __launch_bounds__(256) void ln_kernel(const ushortb* __restrict__ in,
                                                 const float* __restrict__ g,
                                                 const float* __restrict__ bta,
                                                 ushortb* __restrict__ out)
{
    const int lane = threadIdx.x & 63, w = threadIdx.x >> 6;
    const size_t row = (size_t)blockIdx.x * 4 + w;
    const int e0 = lane * 8;
    short8 v8 = *(const short8*)(in + row * 512 + e0);
    float v[8];
    #pragma unroll
    for (int k = 0; k < 8; ++k) v[k] = bb2f((ushortb)((short*)&v8)[k]);
    float s = 0.f, sq = 0.f;
    #pragma unroll
    for (int k = 0; k < 8; ++k) { s += v[k]; sq += v[k] * v[k]; }
    #pragma unroll
    for (int o = 1; o < 64; o <<= 1) { s += __shfl_xor(s, o); sq += __shfl_xor(sq, o); }
    float mu = s * (1.0f / 512.0f);
    float var = sq * (1.0f / 512.0f) - mu * mu;
    float rstd = rsqrtf(var + 1e-5f);
    float4 g0 = *(const float4*)(g + e0),  g1 = *(const float4*)(g + e0 + 4);
    float4 b0 = *(const float4*)(bta + e0), b1 = *(const float4*)(bta + e0 + 4);
    float gg[8] = {g0.x, g0.y, g0.z, g0.w, g1.x, g1.y, g1.z, g1.w};
    float bb[8] = {b0.x, b0.y, b0.z, b0.w, b1.x, b1.y, b1.z, b1.w};
    short8 o8;
    #pragma unroll
    for (int k = 0; k < 8; ++k)
        ((short*)&o8)[k] = (short)f2bb((v[k] - mu) * rstd * gg[k] + bb[k]);
    *(short8*)(out + row * 512 + e0) = o8;
}

// ---------------------------------------------------------------------------
// MaxPool1d(16) + FC[32768,2] partial: grid (16 batch, 16 chunks), atomicAdd.
__global__ __launch_bounds__(256) void final_partial(const ushortb* __restrict__ ln2,
                                                     const float* __restrict__ fcw,
                                                     float* __restrict__ zbuf)
{
    const int b = blockIdx.x, chunk = blockIdx.y;
    const int tid = threadIdx.x;
    float a0 = 0.0f, a1 = 0.0f;
    #pragma unroll
    for (int t = 0; t < 8; ++t) {
        int m = chunk * 2048 + t * 256 + tid;
        int s = m >> 5, j = m & 31;
        const ushortb* p = ln2 + (((size_t)(b * 1024 + s)) << 9) + j * 16;
        float mx = -1e30f;
        #pragma unroll
        for (int e = 0; e < 16; ++e) mx = fmaxf(mx, bb2f(p[e]));
        a0 += mx * fcw[2 * m];
        a1 += mx * fcw[2 * m + 1];
    }
    __shared__ float r0[256], r1[256];
    r0[tid] = a0; r1[tid] = a1;
    __syncthreads();
    for (int o = 128; o > 0; o >>= 1) {
        if (tid < o) { r0[tid] += r0[tid + o]; r1[tid] += r1[tid + o]; }
        __syncthreads();
    }
    if (tid == 0) {
        atomicAdd(&zbuf[2 * b],     r0[0]);
        atomicAdd(&zbuf[2 * b + 1], r1[0]);
    }
}

__global__ __launch_bounds__(64) void final_logits(const float* __restrict__ zbuf,
                                                   const float* __restrict__ fcb,
                                                   float* __restrict__ out)
{
    int b = threadIdx.x;
    if (b < 16) {
        float z0 = zbuf[2 * b]     + fcb[0];
        float z1 = zbuf[2 * b + 1] + fcb[1];
        float mx = fmaxf(z0, z1);
        float lse = mx + logf(expf(z0 - mx) + expf(z1 - mx));
        out[2 * b]     = z0 - lse;
        out[2 * b + 1] = z1 - lse;
    }
}

// ---------------------------------------------------------------------------
extern "C" void kernel_launch(void* const* d_in, const int* in_sizes, int n_in,
                              void* d_out, int out_size, void* d_ws, size_t ws_size,
                              hipStream_t stream)
{
    const float* x     = (const float*)d_in[0];
    const float* emb_w = (const float*)d_in[1];
    const float* emb_b = (const float*)d_in[2];
    const float* WQ    = (const float*)d_in[3];
    const float* WK    = (const float*)d_in[4];
    const float* WV    = (const float*)d_in[5];
    const float* WO    = (const float*)d_in[6];
    const float* g1    = (const float*)d_in[7];
    const float* b1    = (const float*)d_in[8];
    const float* l1w   = (const float*)d_in[9];
    const float* l1b   = (const float*)d_in[10];
    const float* l2w   = (const float*)d_in[11];
    const float* l2b   = (const float*)d_in[12];
    const float* g2    = (const float*)d_in[13];
    const float* b2    = (const float*)d_in[14];
    const float* fcw   = (const float*)d_in[15];
    const float* fcb   = (const float*)d_in[16];
    float* out = (float*)d_out;

    char* ws = (char*)d_ws;
    const size_t Ub = (size_t)16384 * 512 * 2;   // 16.78 MB bf16 activation unit
    // u0: xb -> r1 -> r2   u1: h0b -> ln2   u2: Qb -> ln1
    // u3: Kb -> mid[0]     u4: Vt -> mid[1] u5: headR -> mid[2]  u6: mid[3]
    // NOTE: h0b,Qb,Kb,Vt contiguous (u1..u4) — EP_MEGA writes all four.
    ushortb* xb    = (ushortb*)(ws + 0 * Ub);
    ushortb* h0b   = (ushortb*)(ws + 1 * Ub);
    ushortb* Qb    = (ushortb*)(ws + 2 * Ub);
    ushortb* Kb    = (ushortb*)(ws + 3 * Ub);
    ushortb* Vt    = (ushortb*)(ws + 4 * Ub);
    ushortb* headR = (ushortb*)(ws + 5 * Ub);
    ushortb* mid   = (ushortb*)(ws + 3 * Ub);   // [16384,2048] over u3..u6
    ushortb* r1    = xb;
    ushortb* ln1   = Qb;
    ushortb* r2    = xb;
    ushortb* ln2   = h0b;
    char* wb = ws + 7 * Ub;
    ushortb* WB    = (ushortb*)(wb);                 // [2048][512]: embwt | W2t
    ushortb* W2t   = WB + (size_t)512 * 512;
    ushortb* wqkvt = (ushortb*)(wb + 2097152);       // [1536][512]
    ushortb* embc  = (ushortb*)(wb + 3670016);       // [512][512] emb_w bf16 (no T)
    ushortb* wot   = (ushortb*)(wb + 4194304);       // [512][512]
    ushortb* l1wt  = (ushortb*)(wb + 4718592);       // [2048][512]
    ushortb* l2wt  = (ushortb*)(wb + 6815744);       // [512][2048]
    ushortb* peb   = (ushortb*)(wb + 8912896);       // [1024][512] bf16
    ushortb* peqkv = (ushortb*)(wb + 9961472);       // [1024][1536] bf16
    float*   zbuf  = (float*)  (wb + 13107200);      // [16][2]

    const int M = 16384;
    const float qscale = 0.12753139626997592f;  // log2(e)/sqrt(128)

    // prep: conversions / transposes / tables
    conv_b<<<8192, 256, 0, stream>>>(x, xb);
    conv_b<<<256, 256, 0, stream>>>(emb_w, embc);
    peb_kernel<<<2048, 256, 0, stream>>>(emb_b, peb);
    tileT<<<dim3(8, 8, 1),  256, 0, stream>>>(emb_w, WB, 512, 512, 1.0f);   // embwt
    tileT<<<dim3(2, 8, 4),  256, 0, stream>>>(WQ, wqkvt,          512, 128, qscale);
    tileT<<<dim3(2, 8, 4),  256, 0, stream>>>(WK, wqkvt + 262144, 512, 128, 1.0f);
    tileT<<<dim3(2, 8, 4),  256, 0, stream>>>(WV, wqkvt + 524288, 512, 128, 1.0f);
    tileT<<<dim3(8, 8, 1),  256, 0, stream>>>(WO, wot, 512, 512, 1.0f);
    tileT<<<dim3(32, 8, 1), 256, 0, stream>>>(l1w, l1wt, 512, 2048, 1.0f);
    tileT<<<dim3(8, 32, 1), 256, 0, stream>>>(l2w, l2wt, 2048, 512, 1.0f);
    hipMemsetAsync(zbuf, 0, 16 * 2 * sizeof(float), stream);

    // small prep GEMMs: W2t[n][c] = sum_d wqkvt[n][d]*emb_w[c][d];
    // peqkv[s][n] = sum_d peb[s][d]*wqkvt[n][d]
    gemm_mfma<EP_ST><<<dim3(12, 4), 256, 0, stream>>>(
        wqkvt, embc, nullptr, nullptr, nullptr, nullptr, W2t, 1536, 512, 512);
    gemm_mfma<EP_ST><<<dim3(8, 12), 256, 0, stream>>>(
        peb, wqkvt, nullptr, nullptr, nullptr, nullptr, peqkv, 1024, 1536, 512);

    // 1+2) mega GEMM: x @ [embwt|W2t]^T -> h0 | Q | K | V(transposed)
    gemm_mfma<EP_MEGA><<<dim3(M / 128, 16), 256, 0, stream>>>(
        xb, WB, nullptr, nullptr, peb, peqkv, h0b, M, 2048, 512);

    // 3) flash attention -> headR bf16 ([B,H,S,DK] flat == raw reshape)
    attn_mfma<<<512, 256, 0, stream>>>(Qb, Kb, Vt, headR);

    // 4) r1 = headR @ WO + h0 ; ln1 = LN(r1)
    gemm_mfma<EP_RES><<<dim3(M / 128, 4), 256, 0, stream>>>(
        headR, wot, nullptr, h0b, nullptr, nullptr, r1, M, 512, 512);
    ln_kernel<<<M / 4, 256, 0, stream>>>(r1, g1, b1, ln1);

    // 5) FFN
    gemm_mfma<EP_BIAS_RELU><<<dim3(M / 128, 16), 256, 0, stream>>>(
        ln1, l1wt, l1b, nullptr, nullptr, nullptr, mid, M, 2048, 512);
    gemm_mfma<EP_BIAS_RES><<<dim3(M / 128, 4), 256, 0, stream>>>(
        mid, l2wt, l2b, ln1, nullptr, nullptr, r2, M, 512, 2048);
    ln_kernel<<<M / 4, 256, 0, stream>>>(r2, g2, b2, ln2);

    // 6) maxpool + FC + log_softmax
    final_partial<<<dim3(16, 16), 256, 0, stream>>>(ln2, fcw, zbuf);
    final_logits<<<1, 64, 0, stream>>>(zbuf, fcb, out);
}

// Round 11
// 367.274 us; speedup vs baseline: 1.1126x; 1.1126x over previous
//
#include <hip/hip_runtime.h>

typedef unsigned short ushortb;
typedef __attribute__((ext_vector_type(8))) short short8;    // 8 bf16 = 16B (MFMA A/B frag)
typedef __attribute__((ext_vector_type(4))) float f32x4;     // MFMA C/D frag

__device__ __forceinline__ ushortb f2bb(float f) {
    union { float f; unsigned u; } x; x.f = f;
    unsigned r = x.u + 0x7fffu + ((x.u >> 16) & 1u);   // RNE
    return (ushortb)(r >> 16);
}
__device__ __forceinline__ float bb2f(ushortb u) {
    union { unsigned u; float f; } x; x.u = ((unsigned)u) << 16; return x.f;
}

// async global->LDS DMA, 16B/lane; lds base wave-uniform, lane -> base+lane*16
__device__ __forceinline__ void async_ld16(void* lds, const void* g) {
    __builtin_amdgcn_global_load_lds(
        (const __attribute__((address_space(1))) void*)g,
        (__attribute__((address_space(3))) void*)lds, 16, 0, 0);
}

// ---------------------------------------------------------------------------
#define EP_EMB       0   // + bias + pe table
#define EP_RES       2   // + bf16 residual
#define EP_BIAS_RELU 3   // + bias, relu
#define EP_BIAS_RES  4   // + bias + bf16 residual
#define EP_QKV       7   // N=1536 fused: cols<1024 -> Qb/Kb, cols>=1024 -> Vt transposed

// C[M,N] = A[M,K] @ Bt[N,K]^T (+ epilogue). bf16 in, fp32 MFMA accum, bf16 out.
// Block 256 thr (4 waves 2x2), tile 128x128, BK=64, DOUBLE-BUFFERED
// global_load_lds staging (issue tile k+1 before computing tile k -> the
// vmcnt(0) drain at the barrier overlaps the MFMA work). XOR-swizzled
// unpadded LDS: chunk c of row r at slot c ^ ((r^(r>>3))&7).
template <int EP>
__global__ __launch_bounds__(256) void gemm_mfma(
    const ushortb* __restrict__ A, const ushortb* __restrict__ Bt,
    const float* __restrict__ bias, const ushortb* __restrict__ res,
    const float* __restrict__ pe, ushortb* __restrict__ C,
    int M, int N, int K)
{
    __shared__ ushortb sA[2][128][64];   // 32 KB
    __shared__ ushortb sB[2][128][64];   // 32 KB

    const int tid = threadIdx.x;
    const int wave = tid >> 6, lane = tid & 63;
    const int quad = lane >> 4, l15 = lane & 15;
    const int row0 = blockIdx.x * 128;
    const int col0 = blockIdx.y * 128;
    const int wm = (wave >> 1) * 64, wn = (wave & 1) * 64;
    const int srl = lane >> 3, slot = lane & 7;

    f32x4 acc[4][4];
    #pragma unroll
    for (int i = 0; i < 4; ++i)
        #pragma unroll
        for (int j = 0; j < 4; ++j) acc[i][j] = (f32x4){0.f, 0.f, 0.f, 0.f};

    // initial stage -> buffer 0
    #pragma unroll
    for (int c = 0; c < 4; ++c) {
        int rbase = wave * 32 + c * 8;
        int r = rbase + srl;
        int ka = (slot ^ ((r ^ (r >> 3)) & 7)) * 8;
        async_ld16(&sA[0][rbase][0], A  + (size_t)(row0 + r) * K + ka);
        async_ld16(&sB[0][rbase][0], Bt + (size_t)(col0 + r) * K + ka);
    }

    int buf = 0;
    for (int k0 = 0; k0 < K; k0 += 64) {
        __syncthreads();   // drains DMA for 'buf' (issued one iter ago) + prev compute
        if (k0 + 64 < K) {
            int nb = buf ^ 1;
            #pragma unroll
            for (int c = 0; c < 4; ++c) {
                int rbase = wave * 32 + c * 8;
                int r = rbase + srl;
                int ka = (slot ^ ((r ^ (r >> 3)) & 7)) * 8;
                async_ld16(&sA[nb][rbase][0], A  + (size_t)(row0 + r) * K + k0 + 64 + ka);
                async_ld16(&sB[nb][rbase][0], Bt + (size_t)(col0 + r) * K + k0 + 64 + ka);
            }
        }
        #pragma unroll
        for (int kc = 0; kc < 2; ++kc) {
            short8 af[4], bf[4];
            #pragma unroll
            for (int i = 0; i < 4; ++i) {
                int m = wm + i * 16 + l15;
                af[i] = *(const short8*)&sA[buf][m][(((kc * 4 + quad) ^ ((m ^ (m >> 3)) & 7))) * 8];
            }
            #pragma unroll
            for (int j = 0; j < 4; ++j) {
                int n = wn + j * 16 + l15;
                bf[j] = *(const short8*)&sB[buf][n][(((kc * 4 + quad) ^ ((n ^ (n >> 3)) & 7))) * 8];
            }
            #pragma unroll
            for (int i = 0; i < 4; ++i)
                #pragma unroll
                for (int j = 0; j < 4; ++j)
                    acc[i][j] = __builtin_amdgcn_mfma_f32_16x16x32_bf16(af[i], bf[j], acc[i][j], 0, 0, 0);
        }
        buf ^= 1;
    }

    if constexpr (EP == EP_QKV) {
        if (col0 < 1024) {
            // Q (cols 0..511) or K (512..1023); Qb/Kb consecutive M*512 buffers
            ushortb* dst = C + ((size_t)(col0 >> 9)) * ((size_t)M * 512);
            #pragma unroll
            for (int i = 0; i < 4; ++i)
                #pragma unroll
                for (int r = 0; r < 4; ++r) {
                    int row = row0 + wm + i * 16 + quad * 4 + r;
                    #pragma unroll
                    for (int j = 0; j < 4; ++j) {
                        int col = (col0 + wn + j * 16 + l15) & 511;
                        dst[(size_t)row * 512 + col] = f2bb(acc[i][j][r]);
                    }
                }
        } else {
            // V: row=b*1024+s, vcol=h*128+e -> Vt[(b*4+h)*128+e][s]
            ushortb* Vt = C + (size_t)2 * M * 512;
            int bb_ = row0 >> 10;
            #pragma unroll
            for (int i = 0; i < 4; ++i) {
                int s = (row0 & 1023) + wm + i * 16 + quad * 4;
                #pragma unroll
                for (int j = 0; j < 4; ++j) {
                    int vcol = col0 + wn + j * 16 + l15 - 1024;
                    int h = vcol >> 7, e = vcol & 127;
                    ushort4 v;
                    v.x = f2bb(acc[i][j][0]); v.y = f2bb(acc[i][j][1]);
                    v.z = f2bb(acc[i][j][2]); v.w = f2bb(acc[i][j][3]);
                    *(ushort4*)&Vt[((size_t)((bb_ * 4 + h) * 128 + e) << 10) + s] = v;
                }
            }
        }
        return;
    }

    #pragma unroll
    for (int i = 0; i < 4; ++i) {
        #pragma unroll
        for (int r = 0; r < 4; ++r) {
            int row = row0 + wm + i * 16 + quad * 4 + r;
            #pragma unroll
            for (int j = 0; j < 4; ++j) {
                int col = col0 + wn + j * 16 + l15;
                float v = acc[i][j][r];
                if constexpr (EP == EP_EMB) {
                    v += bias[col] + pe[((row & 1023) << 9) + col];
                } else if constexpr (EP == EP_RES) {
                    v += bb2f(res[(size_t)row * N + col]);
                } else if constexpr (EP == EP_BIAS_RELU) {
                    v = fmaxf(v + bias[col], 0.0f);
                } else if constexpr (EP == EP_BIAS_RES) {
                    v += bias[col] + bb2f(res[(size_t)row * N + col]);
                }
                C[(size_t)row * N + col] = f2bb(v);
            }
        }
    }
}

// ---------------------------------------------------------------------------
// Prep: x fp32 -> bf16
__global__ __launch_bounds__(256) void conv_x(const float* __restrict__ in,
                                              ushortb* __restrict__ out)
{
    size_t i4 = (size_t)blockIdx.x * 256 + threadIdx.x;
    float4 v = *(const float4*)(in + i4 * 4);
    ushort4 o;
    o.x = f2bb(v.x); o.y = f2bb(v.y); o.z = f2bb(v.z); o.w = f2bb(v.w);
    *(ushort4*)(out + i4 * 4) = o;
}

// LDS-tiled transpose-convert: in fp32 [R][C] (+z*R*C) -> out bf16 [C][R] (+z*R*C), *scale.
__global__ __launch_bounds__(256) void tileT(const float* __restrict__ in,
                                             ushortb* __restrict__ out,
                                             int R, int C, float scale)
{
    __shared__ float t[64][65];
    const int tx = threadIdx.x & 63, ty = threadIdx.x >> 6;
    const int c0 = blockIdx.x * 64, r0 = blockIdx.y * 64;
    const size_t zoff = (size_t)blockIdx.z * R * C;
    #pragma unroll
    for (int i = 0; i < 16; ++i) {
        int r = ty + i * 4;
        t[r][tx] = in[zoff + (size_t)(r0 + r) * C + c0 + tx] * scale;
    }
    __syncthreads();
    #pragma unroll
    for (int i = 0; i < 16; ++i) {
        int r = ty + i * 4;
        out[zoff + (size_t)(c0 + r) * R + r0 + tx] = f2bb(t[tx][r]);
    }
}

// positional encoding table fp32 [1024][512]
__global__ __launch_bounds__(256) void pe_kernel(float* __restrict__ pe)
{
    int idx = blockIdx.x * 256 + threadIdx.x;    // s*512 + c
    int s = idx >> 9, c = idx & 511;
    float div = expf((float)(c & ~1) * (-9.210340371976184f / 512.0f));
    float ang = (float)s * div;
    pe[idx] = (c & 1) ? cosf(ang) : sinf(ang);
}

// ---------------------------------------------------------------------------
// MFMA flash attention, fixed-max softmax, DOUBLE-BUFFERED DMA-staged K/V,
// XCD-local grid. Q pre-scaled by log2(e)/sqrt(128) so p = exp2(score).
// Block = 128 q (32/wave). One barrier per K/V tile.
__global__ __launch_bounds__(256) void attn_mfma(
    const ushortb* __restrict__ Qb, const ushortb* __restrict__ Kb,
    const ushortb* __restrict__ Vt, ushortb* __restrict__ O)
{
    __shared__ ushortb sK[2][32][128];    // 16 KB
    __shared__ ushortb sVt[2][128][32];   // 16 KB
    __shared__ ushortb sP[4][32][40];     // 10 KB, [wave][q_local][t]

    const int tid = threadIdx.x;
    const int wave = tid >> 6, lane = tid & 63;
    const int quad = lane >> 4, l15 = lane & 15;
    const int bid = blockIdx.x;          // XCD swizzle: same (b,h) -> ids 64 apart
    const int bh = bid & 63, qc = bid >> 6;
    const int b = bh >> 2, h = bh & 3;
    const int q0 = qc * 128 + wave * 32;
    const size_t qk_off = ((size_t)b << 10) * 512 + h * 128;
    const ushortb* Qp = Qb + qk_off;
    const ushortb* Kp = Kb + qk_off;
    const ushortb* Vp = Vt + (((size_t)(b * 4 + h)) << 17);

    short8 qfA[4], qfB[4];   // B-frags: Q[q=l15 | 16+l15][k=quad*8+j]
    {
        const ushortb* qa = Qp + (size_t)(q0 + l15) * 512;
        const ushortb* qb = Qp + (size_t)(q0 + 16 + l15) * 512;
        #pragma unroll
        for (int kc = 0; kc < 4; ++kc) {
            qfA[kc] = *(const short8*)(qa + kc * 32 + quad * 8);
            qfB[kc] = *(const short8*)(qb + kc * 32 + quad * 8);
        }
    }

    f32x4 oA[8], oB[8];
    #pragma unroll
    for (int dt = 0; dt < 8; ++dt) {
        oA[dt] = (f32x4){0.f, 0.f, 0.f, 0.f};
        oB[dt] = (f32x4){0.f, 0.f, 0.f, 0.f};
    }
    float lA = 0.f, lB = 0.f;

    // initial stage -> buffer 0 (tile t0=0)
    #pragma unroll
    for (int c = 0; c < 2; ++c) {
        int seg = wave * 2 + c;
        int rk = seg * 4 + (lane >> 4);
        int ck = (lane & 15) ^ (rk & 15);
        async_ld16(&sK[0][seg * 4][0], Kp + (size_t)rk * 512 + ck * 8);
        int dv = seg * 16 + (lane >> 2);
        int cv = (lane & 3) ^ (dv & 3);
        async_ld16(&sVt[0][seg * 16][0], Vp + ((size_t)dv << 10) + cv * 8);
    }

    int buf = 0;
    for (int t0 = 0; t0 < 1024; t0 += 32) {
        __syncthreads();   // DMA for 'buf' complete + prev compute done
        if (t0 + 32 < 1024) {
            int nb = buf ^ 1;
            #pragma unroll
            for (int c = 0; c < 2; ++c) {
                int seg = wave * 2 + c;
                int rk = seg * 4 + (lane >> 4);
                int ck = (lane & 15) ^ (rk & 15);
                async_ld16(&sK[nb][seg * 4][0], Kp + (size_t)(t0 + 32 + rk) * 512 + ck * 8);
                int dv = seg * 16 + (lane >> 2);
                int cv = (lane & 3) ^ (dv & 3);
                async_ld16(&sVt[nb][seg * 16][0], Vp + ((size_t)dv << 10) + t0 + 32 + cv * 8);
            }
        }

        // S^T: D[t][q]; t = quad*4+reg (+0/16), q = l15 (A-group) / 16+l15 (B)
        f32x4 sA0 = {0,0,0,0}, sA1 = {0,0,0,0}, sB0 = {0,0,0,0}, sB1 = {0,0,0,0};
        #pragma unroll
        for (int kc = 0; kc < 4; ++kc) {
            short8 k0f = *(const short8*)&sK[buf][l15][((kc * 4 + quad) ^ l15) * 8];
            short8 k1f = *(const short8*)&sK[buf][16 + l15][((kc * 4 + quad) ^ l15) * 8];
            sA0 = __builtin_amdgcn_mfma_f32_16x16x32_bf16(k0f, qfA[kc], sA0, 0, 0, 0);
            sA1 = __builtin_amdgcn_mfma_f32_16x16x32_bf16(k1f, qfA[kc], sA1, 0, 0, 0);
            sB0 = __builtin_amdgcn_mfma_f32_16x16x32_bf16(k0f, qfB[kc], sB0, 0, 0, 0);
            sB1 = __builtin_amdgcn_mfma_f32_16x16x32_bf16(k1f, qfB[kc], sB1, 0, 0, 0);
        }

        float pA0[4], pA1[4], pB0[4], pB1[4];
        float sumA = 0.f, sumB = 0.f;
        #pragma unroll
        for (int r = 0; r < 4; ++r) {
            pA0[r] = exp2f(sA0[r]); pA1[r] = exp2f(sA1[r]);
            pB0[r] = exp2f(sB0[r]); pB1[r] = exp2f(sB1[r]);
            sumA += pA0[r] + pA1[r];
            sumB += pB0[r] + pB1[r];
        }
        lA += sumA; lB += sumB;

        ushort4 w;
        w.x = f2bb(pA0[0]); w.y = f2bb(pA0[1]); w.z = f2bb(pA0[2]); w.w = f2bb(pA0[3]);
        *(ushort4*)&sP[wave][l15][quad * 4] = w;
        w.x = f2bb(pA1[0]); w.y = f2bb(pA1[1]); w.z = f2bb(pA1[2]); w.w = f2bb(pA1[3]);
        *(ushort4*)&sP[wave][l15][16 + quad * 4] = w;
        w.x = f2bb(pB0[0]); w.y = f2bb(pB0[1]); w.z = f2bb(pB0[2]); w.w = f2bb(pB0[3]);
        *(ushort4*)&sP[wave][16 + l15][quad * 4] = w;
        w.x = f2bb(pB1[0]); w.y = f2bb(pB1[1]); w.z = f2bb(pB1[2]); w.w = f2bb(pB1[3]);
        *(ushort4*)&sP[wave][16 + l15][16 + quad * 4] = w;

        short8 pfA = *(const short8*)&sP[wave][l15][quad * 8];
        short8 pfB = *(const short8*)&sP[wave][16 + l15][quad * 8];

        #pragma unroll
        for (int dt = 0; dt < 8; ++dt) {
            int d = dt * 16 + l15;
            short8 vfrag = *(const short8*)&sVt[buf][d][(quad ^ (d & 3)) * 8];
            oA[dt] = __builtin_amdgcn_mfma_f32_16x16x32_bf16(pfA, vfrag, oA[dt], 0, 0, 0);
            oB[dt] = __builtin_amdgcn_mfma_f32_16x16x32_bf16(pfB, vfrag, oB[dt], 0, 0, 0);
        }
        buf ^= 1;
    }

    lA += __shfl_xor(lA, 16); lA += __shfl_xor(lA, 32);
    lB += __shfl_xor(lB, 16); lB += __shfl_xor(lB, 32);

    const size_t obase = (((size_t)(b * 4 + h) << 10) + q0) << 7;
    #pragma unroll
    for (int r = 0; r < 4; ++r) {
        float invA = 1.0f / __shfl(lA, quad * 4 + r);
        float invB = 1.0f / __shfl(lB, quad * 4 + r);
        int qa = quad * 4 + r, qb = 16 + quad * 4 + r;
        #pragma unroll
        for (int dt = 0; dt < 8; ++dt) {
            O[obase + ((size_t)qa << 7) + dt * 16 + l15] = f2bb(oA[dt][r] * invA);
            O[obase + ((size_t)qb << 7) + dt * 16 + l15] = f2bb(oB[dt][r] * invB);
        }
    }
}

// ---------------------------------------------------------------------------
// LayerNorm over 512 features: wave per row, 8 elems/lane, shuffle reduce.
__global__ __launch_bounds__(256) void ln_kernel(const ushortb* __restrict__ in,
                                                 const float* __restrict__ g,
                                                 const float* __restrict__ bta,
                                                 ushortb* __restrict__ out)
{
    const int lane = threadIdx.x & 63, w = threadIdx.x >> 6;
    const size_t row = (size_t)blockIdx.x * 4 + w;
    const int e0 = lane * 8;
    short8 v8 = *(const short8*)(in + row * 512 + e0);
    float v[8];
    #pragma unroll
    for (int k = 0; k < 8; ++k) v[k] = bb2f((ushortb)((short*)&v8)[k]);
    float s = 0.f, sq = 0.f;
    #pragma unroll
    for (int k = 0; k < 8; ++k) { s += v[k]; sq += v[k] * v[k]; }
    #pragma unroll
    for (int o = 1; o < 64; o <<= 1) { s += __shfl_xor(s, o); sq += __shfl_xor(sq, o); }
    float mu = s * (1.0f / 512.0f);
    float var = sq * (1.0f / 512.0f) - mu * mu;
    float rstd = rsqrtf(var + 1e-5f);
    float4 g0 = *(const float4*)(g + e0),  g1 = *(const float4*)(g + e0 + 4);
    float4 b0 = *(const float4*)(bta + e0), b1 = *(const float4*)(bta + e0 + 4);
    float gg[8] = {g0.x, g0.y, g0.z, g0.w, g1.x, g1.y, g1.z, g1.w};
    float bb[8] = {b0.x, b0.y, b0.z, b0.w, b1.x, b1.y, b1.z, b1.w};
    short8 o8;
    #pragma unroll
    for (int k = 0; k < 8; ++k)
        ((short*)&o8)[k] = (short)f2bb((v[k] - mu) * rstd * gg[k] + bb[k]);
    *(short8*)(out + row * 512 + e0) = o8;
}

// ---------------------------------------------------------------------------
// MaxPool1d(16) + FC[32768,2] partial: grid (16 batch, 16 chunks), atomicAdd.
__global__ __launch_bounds__(256) void final_partial(const ushortb* __restrict__ ln2,
                                                     const float* __restrict__ fcw,
                                                     float* __restrict__ zbuf)
{
    const int b = blockIdx.x, chunk = blockIdx.y;
    const int tid = threadIdx.x;
    float a0 = 0.0f, a1 = 0.0f;
    #pragma unroll
    for (int t = 0; t < 8; ++t) {
        int m = chunk * 2048 + t * 256 + tid;
        int s = m >> 5, j = m & 31;
        const ushortb* p = ln2 + (((size_t)(b * 1024 + s)) << 9) + j * 16;
        float mx = -1e30f;
        #pragma unroll
        for (int e = 0; e < 16; ++e) mx = fmaxf(mx, bb2f(p[e]));
        a0 += mx * fcw[2 * m];
        a1 += mx * fcw[2 * m + 1];
    }
    __shared__ float r0[256], r1[256];
    r0[tid] = a0; r1[tid] = a1;
    __syncthreads();
    for (int o = 128; o > 0; o >>= 1) {
        if (tid < o) { r0[tid] += r0[tid + o]; r1[tid] += r1[tid + o]; }
        __syncthreads();
    }
    if (tid == 0) {
        atomicAdd(&zbuf[2 * b],     r0[0]);
        atomicAdd(&zbuf[2 * b + 1], r1[0]);
    }
}

__global__ __launch_bounds__(64) void final_logits(const float* __restrict__ zbuf,
                                                   const float* __restrict__ fcb,
                                                   float* __restrict__ out)
{
    int b = threadIdx.x;
    if (b < 16) {
        float z0 = zbuf[2 * b]     + fcb[0];
        float z1 = zbuf[2 * b + 1] + fcb[1];
        float mx = fmaxf(z0, z1);
        float lse = mx + logf(expf(z0 - mx) + expf(z1 - mx));
        out[2 * b]     = z0 - lse;
        out[2 * b + 1] = z1 - lse;
    }
}

// ---------------------------------------------------------------------------
extern "C" void kernel_launch(void* const* d_in, const int* in_sizes, int n_in,
                              void* d_out, int out_size, void* d_ws, size_t ws_size,
                              hipStream_t stream)
{
    const float* x     = (const float*)d_in[0];
    const float* emb_w = (const float*)d_in[1];
    const float* emb_b = (const float*)d_in[2];
    const float* WQ    = (const float*)d_in[3];
    const float* WK    = (const float*)d_in[4];
    const float* WV    = (const float*)d_in[5];
    const float* WO    = (const float*)d_in[6];
    const float* g1    = (const float*)d_in[7];
    const float* b1    = (const float*)d_in[8];
    const float* l1w   = (const float*)d_in[9];
    const float* l1b   = (const float*)d_in[10];
    const float* l2w   = (const float*)d_in[11];
    const float* l2b   = (const float*)d_in[12];
    const float* g2    = (const float*)d_in[13];
    const float* b2    = (const float*)d_in[14];
    const float* fcw   = (const float*)d_in[15];
    const float* fcb   = (const float*)d_in[16];
    float* out = (float*)d_out;

    char* ws = (char*)d_ws;
    const size_t Ub = (size_t)16384 * 512 * 2;   // 16.78 MB bf16 activation unit
    // u0: xb -> r1 -> r2   u1: h0b -> ln2   u2: Qb -> ln1
    // u3: Kb -> mid[0]     u4: Vt -> mid[1] u5: headR -> mid[2]  u6: mid[3]
    ushortb* xb    = (ushortb*)(ws + 0 * Ub);
    ushortb* h0b   = (ushortb*)(ws + 1 * Ub);
    ushortb* Qb    = (ushortb*)(ws + 2 * Ub);   // Kb = Qb + M*512, Vt = Qb + 2*M*512
    ushortb* Kb    = (ushortb*)(ws + 3 * Ub);
    ushortb* Vt    = (ushortb*)(ws + 4 * Ub);
    ushortb* headR = (ushortb*)(ws + 5 * Ub);
    ushortb* mid   = (ushortb*)(ws + 3 * Ub);   // [16384,2048] over u3..u6
    ushortb* r1    = xb;
    ushortb* ln1   = Qb;
    ushortb* r2    = xb;
    ushortb* ln2   = h0b;
    char* wb = ws + 7 * Ub;
    ushortb* embwt = (ushortb*)(wb);                        // [512][512]
    ushortb* wqkvt = (ushortb*)(wb + 524288);               // [1536][512]
    ushortb* wot   = (ushortb*)(wb + 2097152);              // [512][512]
    ushortb* l1wt  = (ushortb*)(wb + 2621440);              // [2048][512]
    ushortb* l2wt  = (ushortb*)(wb + 4718592);              // [512][2048]
    float*   pe    = (float*)  (wb + 6815744);              // [1024][512] fp32
    float*   zbuf  = (float*)  (wb + 8912896);              // [16][2]

    const int M = 16384;
    const float qscale = 0.12753139626997592f;  // log2(e)/sqrt(128)

    // prep
    conv_x<<<8192, 256, 0, stream>>>(x, xb);
    pe_kernel<<<2048, 256, 0, stream>>>(pe);
    tileT<<<dim3(8, 8, 1),  256, 0, stream>>>(emb_w, embwt, 512, 512, 1.0f);
    tileT<<<dim3(2, 8, 4),  256, 0, stream>>>(WQ, wqkvt,          512, 128, qscale);
    tileT<<<dim3(2, 8, 4),  256, 0, stream>>>(WK, wqkvt + 262144, 512, 128, 1.0f);
    tileT<<<dim3(2, 8, 4),  256, 0, stream>>>(WV, wqkvt + 524288, 512, 128, 1.0f);
    tileT<<<dim3(8, 8, 1),  256, 0, stream>>>(WO, wot, 512, 512, 1.0f);
    tileT<<<dim3(32, 8, 1), 256, 0, stream>>>(l1w, l1wt, 512, 2048, 1.0f);
    tileT<<<dim3(8, 32, 1), 256, 0, stream>>>(l2w, l2wt, 2048, 512, 1.0f);
    hipMemsetAsync(zbuf, 0, 16 * 2 * sizeof(float), stream);

    // 1) h0 = x @ emb_w + emb_b + pe
    gemm_mfma<EP_EMB><<<dim3(M / 128, 4), 256, 0, stream>>>(
        xb, embwt, emb_b, nullptr, pe, h0b, M, 512, 512);

    // 2) fused QKV projection (Q scale baked; V transposed in epilogue)
    gemm_mfma<EP_QKV><<<dim3(M / 128, 12), 256, 0, stream>>>(
        h0b, wqkvt, nullptr, nullptr, nullptr, Qb, M, 1536, 512);

    // 3) flash attention -> headR bf16 ([B,H,S,DK] flat == raw reshape)
    attn_mfma<<<512, 256, 0, stream>>>(Qb, Kb, Vt, headR);

    // 4) r1 = headR @ WO + h0 ; ln1 = LN(r1)
    gemm_mfma<EP_RES><<<dim3(M / 128, 4), 256, 0, stream>>>(
        headR, wot, nullptr, h0b, nullptr, r1, M, 512, 512);
    ln_kernel<<<M / 4, 256, 0, stream>>>(r1, g1, b1, ln1);

    // 5) FFN
    gemm_mfma<EP_BIAS_RELU><<<dim3(M / 128, 16), 256, 0, stream>>>(
        ln1, l1wt, l1b, nullptr, nullptr, mid, M, 2048, 512);
    gemm_mfma<EP_BIAS_RES><<<dim3(M / 128, 4), 256, 0, stream>>>(
        mid, l2wt, l2b, ln1, nullptr, r2, M, 512, 2048);
    ln_kernel<<<M / 4, 256, 0, stream>>>(r2, g2, b2, ln2);

    // 6) maxpool + FC + log_softmax
    final_partial<<<dim3(16, 16), 256, 0, stream>>>(ln2, fcw, zbuf);
    final_logits<<<1, 64, 0, stream>>>(zbuf, fcb, out);
}

// Round 12
// 355.941 us; speedup vs baseline: 1.1480x; 1.0318x over previous
//
#include <hip/hip_runtime.h>

typedef unsigned short ushortb;
typedef __attribute__((ext_vector_type(8))) short short8;    // 8 bf16 = 16B (MFMA A/B frag)
typedef __attribute__((ext_vector_type(4))) float f32x4;     // MFMA C/D frag

__device__ __forceinline__ ushortb f2bb(float f) {
    union { float f; unsigned u; } x; x.f = f;
    unsigned r = x.u + 0x7fffu + ((x.u >> 16) & 1u);   // RNE
    return (ushortb)(r >> 16);
}
__device__ __forceinline__ float bb2f(ushortb u) {
    union { unsigned u; float f; } x; x.u = ((unsigned)u) << 16; return x.f;
}

// packed fp32x2 -> bf16x2 (low|high), RNE. gfx950 v_cvt_pk_bf16_f32 if available.
__device__ __forceinline__ unsigned pkbb(float a, float b) {
#if __has_builtin(__builtin_amdgcn_cvt_pk_bf16_f32)
    auto p = __builtin_amdgcn_cvt_pk_bf16_f32(a, b);
    unsigned u; __builtin_memcpy(&u, &p, 4);
    return u;
#else
    return (unsigned)f2bb(a) | ((unsigned)f2bb(b) << 16);
#endif
}

#if __has_builtin(__builtin_amdgcn_exp2f)
#define EXP2(x) __builtin_amdgcn_exp2f(x)
#else
#define EXP2(x) exp2f(x)
#endif

// async global->LDS DMA, 16B/lane; lds base wave-uniform, lane -> base+lane*16
__device__ __forceinline__ void async_ld16(void* lds, const void* g) {
    __builtin_amdgcn_global_load_lds(
        (const __attribute__((address_space(1))) void*)g,
        (__attribute__((address_space(3))) void*)lds, 16, 0, 0);
}

// ---------------------------------------------------------------------------
#define EP_EMB       0   // + bias + pe table
#define EP_RES       2   // + bf16 residual
#define EP_BIAS_RELU 3   // + bias, relu
#define EP_BIAS_RES  4   // + bias + bf16 residual
#define EP_QKV       7   // N=1536 fused: cols<1024 -> Qb/Kb, cols>=1024 -> Vt transposed

// C[M,N] = A[M,K] @ Bt[N,K]^T (+ epilogue). bf16 in, fp32 MFMA accum, bf16 out.
// Block 256 thr (4 waves 2x2), tile 128x128, BK=64, double-buffered
// global_load_lds staging; XOR-swizzled unpadded LDS.
template <int EP>
__global__ __launch_bounds__(256) void gemm_mfma(
    const ushortb* __restrict__ A, const ushortb* __restrict__ Bt,
    const float* __restrict__ bias, const ushortb* __restrict__ res,
    const float* __restrict__ pe, ushortb* __restrict__ C,
    int M, int N, int K)
{
    __shared__ ushortb sA[2][128][64];   // 32 KB
    __shared__ ushortb sB[2][128][64];   // 32 KB

    const int tid = threadIdx.x;
    const int wave = tid >> 6, lane = tid & 63;
    const int quad = lane >> 4, l15 = lane & 15;
    const int row0 = blockIdx.x * 128;
    const int col0 = blockIdx.y * 128;
    const int wm = (wave >> 1) * 64, wn = (wave & 1) * 64;
    const int srl = lane >> 3, slot = lane & 7;

    f32x4 acc[4][4];
    #pragma unroll
    for (int i = 0; i < 4; ++i)
        #pragma unroll
        for (int j = 0; j < 4; ++j) acc[i][j] = (f32x4){0.f, 0.f, 0.f, 0.f};

    // initial stage -> buffer 0
    #pragma unroll
    for (int c = 0; c < 4; ++c) {
        int rbase = wave * 32 + c * 8;
        int r = rbase + srl;
        int ka = (slot ^ ((r ^ (r >> 3)) & 7)) * 8;
        async_ld16(&sA[0][rbase][0], A  + (size_t)(row0 + r) * K + ka);
        async_ld16(&sB[0][rbase][0], Bt + (size_t)(col0 + r) * K + ka);
    }

    int buf = 0;
    for (int k0 = 0; k0 < K; k0 += 64) {
        __syncthreads();   // drains DMA for 'buf' + prev compute
        if (k0 + 64 < K) {
            int nb = buf ^ 1;
            #pragma unroll
            for (int c = 0; c < 4; ++c) {
                int rbase = wave * 32 + c * 8;
                int r = rbase + srl;
                int ka = (slot ^ ((r ^ (r >> 3)) & 7)) * 8;
                async_ld16(&sA[nb][rbase][0], A  + (size_t)(row0 + r) * K + k0 + 64 + ka);
                async_ld16(&sB[nb][rbase][0], Bt + (size_t)(col0 + r) * K + k0 + 64 + ka);
            }
        }
        #pragma unroll
        for (int kc = 0; kc < 2; ++kc) {
            short8 af[4], bf[4];
            #pragma unroll
            for (int i = 0; i < 4; ++i) {
                int m = wm + i * 16 + l15;
                af[i] = *(const short8*)&sA[buf][m][(((kc * 4 + quad) ^ ((m ^ (m >> 3)) & 7))) * 8];
            }
            #pragma unroll
            for (int j = 0; j < 4; ++j) {
                int n = wn + j * 16 + l15;
                bf[j] = *(const short8*)&sB[buf][n][(((kc * 4 + quad) ^ ((n ^ (n >> 3)) & 7))) * 8];
            }
            #pragma unroll
            for (int i = 0; i < 4; ++i)
                #pragma unroll
                for (int j = 0; j < 4; ++j)
                    acc[i][j] = __builtin_amdgcn_mfma_f32_16x16x32_bf16(af[i], bf[j], acc[i][j], 0, 0, 0);
        }
        buf ^= 1;
    }

    if constexpr (EP == EP_QKV) {
        if (col0 < 1024) {
            ushortb* dst = C + ((size_t)(col0 >> 9)) * ((size_t)M * 512);
            #pragma unroll
            for (int i = 0; i < 4; ++i)
                #pragma unroll
                for (int r = 0; r < 4; ++r) {
                    int row = row0 + wm + i * 16 + quad * 4 + r;
                    #pragma unroll
                    for (int j = 0; j < 4; ++j) {
                        int col = (col0 + wn + j * 16 + l15) & 511;
                        dst[(size_t)row * 512 + col] = f2bb(acc[i][j][r]);
                    }
                }
        } else {
            ushortb* Vt = C + (size_t)2 * M * 512;
            int bb_ = row0 >> 10;
            #pragma unroll
            for (int i = 0; i < 4; ++i) {
                int s = (row0 & 1023) + wm + i * 16 + quad * 4;
                #pragma unroll
                for (int j = 0; j < 4; ++j) {
                    int vcol = col0 + wn + j * 16 + l15 - 1024;
                    int h = vcol >> 7, e = vcol & 127;
                    uint2 v;
                    v.x = pkbb(acc[i][j][0], acc[i][j][1]);
                    v.y = pkbb(acc[i][j][2], acc[i][j][3]);
                    *(uint2*)&Vt[((size_t)((bb_ * 4 + h) * 128 + e) << 10) + s] = v;
                }
            }
        }
        return;
    }

    #pragma unroll
    for (int i = 0; i < 4; ++i) {
        #pragma unroll
        for (int r = 0; r < 4; ++r) {
            int row = row0 + wm + i * 16 + quad * 4 + r;
            #pragma unroll
            for (int j = 0; j < 4; ++j) {
                int col = col0 + wn + j * 16 + l15;
                float v = acc[i][j][r];
                if constexpr (EP == EP_EMB) {
                    v += bias[col] + pe[((row & 1023) << 9) + col];
                } else if constexpr (EP == EP_RES) {
                    v += bb2f(res[(size_t)row * N + col]);
                } else if constexpr (EP == EP_BIAS_RELU) {
                    v = fmaxf(v + bias[col], 0.0f);
                } else if constexpr (EP == EP_BIAS_RES) {
                    v += bias[col] + bb2f(res[(size_t)row * N + col]);
                }
                C[(size_t)row * N + col] = f2bb(v);
            }
        }
    }
}

// ---------------------------------------------------------------------------
// Prep: x fp32 -> bf16
__global__ __launch_bounds__(256) void conv_x(const float* __restrict__ in,
                                              ushortb* __restrict__ out)
{
    size_t i4 = (size_t)blockIdx.x * 256 + threadIdx.x;
    float4 v = *(const float4*)(in + i4 * 4);
    ushort4 o;
    o.x = f2bb(v.x); o.y = f2bb(v.y); o.z = f2bb(v.z); o.w = f2bb(v.w);
    *(ushort4*)(out + i4 * 4) = o;
}

// LDS-tiled transpose-convert: in fp32 [R][C] (+z*R*C) -> out bf16 [C][R] (+z*R*C), *scale.
__global__ __launch_bounds__(256) void tileT(const float* __restrict__ in,
                                             ushortb* __restrict__ out,
                                             int R, int C, float scale)
{
    __shared__ float t[64][65];
    const int tx = threadIdx.x & 63, ty = threadIdx.x >> 6;
    const int c0 = blockIdx.x * 64, r0 = blockIdx.y * 64;
    const size_t zoff = (size_t)blockIdx.z * R * C;
    #pragma unroll
    for (int i = 0; i < 16; ++i) {
        int r = ty + i * 4;
        t[r][tx] = in[zoff + (size_t)(r0 + r) * C + c0 + tx] * scale;
    }
    __syncthreads();
    #pragma unroll
    for (int i = 0; i < 16; ++i) {
        int r = ty + i * 4;
        out[zoff + (size_t)(c0 + r) * R + r0 + tx] = f2bb(t[tx][r]);
    }
}

// merged transpose of emb_w (z=0) and WO (z=1), both [512][512]
__global__ __launch_bounds__(256) void pairT512(const float* __restrict__ emb_w,
                                                const float* __restrict__ WO,
                                                ushortb* __restrict__ embwt,
                                                ushortb* __restrict__ wot)
{
    __shared__ float t[64][65];
    const int tx = threadIdx.x & 63, ty = threadIdx.x >> 6;
    const int c0 = blockIdx.x * 64, r0 = blockIdx.y * 64;
    const float* in = blockIdx.z ? WO : emb_w;
    ushortb* out = blockIdx.z ? wot : embwt;
    #pragma unroll
    for (int i = 0; i < 16; ++i) {
        int r = ty + i * 4;
        t[r][tx] = in[(size_t)(r0 + r) * 512 + c0 + tx];
    }
    __syncthreads();
    #pragma unroll
    for (int i = 0; i < 16; ++i) {
        int r = ty + i * 4;
        out[(size_t)(c0 + r) * 512 + r0 + tx] = f2bb(t[tx][r]);
    }
}

// merged QKV repack: z=0..11, sel=z>>2 in {Q,K,V}, slice zz=z&3 (head).
// Transposes W[sel][zz] fp32 [512][128] -> wqkvt rows, Q scaled.
__global__ __launch_bounds__(256) void qkvT(const float* __restrict__ WQ,
                                            const float* __restrict__ WK,
                                            const float* __restrict__ WV,
                                            ushortb* __restrict__ wqkvt,
                                            float qscale)
{
    __shared__ float t[64][65];
    const int tx = threadIdx.x & 63, ty = threadIdx.x >> 6;
    const int c0 = blockIdx.x * 64, r0 = blockIdx.y * 64;
    const int z = blockIdx.z, sel = z >> 2, zz = z & 3;
    const float* in = (sel == 0 ? WQ : (sel == 1 ? WK : WV)) + (size_t)zz * 65536;
    ushortb* out = wqkvt + (size_t)sel * 262144 + (size_t)zz * 65536;
    const float scale = (sel == 0) ? qscale : 1.0f;
    #pragma unroll
    for (int i = 0; i < 16; ++i) {
        int r = ty + i * 4;
        t[r][tx] = in[(size_t)(r0 + r) * 128 + c0 + tx] * scale;
    }
    __syncthreads();
    #pragma unroll
    for (int i = 0; i < 16; ++i) {
        int r = ty + i * 4;
        out[(size_t)(c0 + r) * 512 + r0 + tx] = f2bb(t[tx][r]);
    }
}

// positional encoding table fp32 [1024][512]
__global__ __launch_bounds__(256) void pe_kernel(float* __restrict__ pe)
{
    int idx = blockIdx.x * 256 + threadIdx.x;    // s*512 + c
    int s = idx >> 9, c = idx & 511;
    float div = expf((float)(c & ~1) * (-9.210340371976184f / 512.0f));
    float ang = (float)s * div;
    pe[idx] = (c & 1) ? cosf(ang) : sinf(ang);
}

// ---------------------------------------------------------------------------
// MFMA flash attention, fixed-max softmax, double-buffered DMA K/V staging,
// XCD-local grid, packed bf16 conversions. Q pre-scaled by log2(e)/sqrt(128).
__global__ __launch_bounds__(256) void attn_mfma(
    const ushortb* __restrict__ Qb, const ushortb* __restrict__ Kb,
    const ushortb* __restrict__ Vt, ushortb* __restrict__ O)
{
    __shared__ ushortb sK[2][32][128];    // 16 KB
    __shared__ ushortb sVt[2][128][32];   // 16 KB
    __shared__ ushortb sP[4][32][40];     // 10 KB, [wave][q_local][t]

    const int tid = threadIdx.x;
    const int wave = tid >> 6, lane = tid & 63;
    const int quad = lane >> 4, l15 = lane & 15;
    const int bid = blockIdx.x;          // XCD swizzle: same (b,h) -> ids 64 apart
    const int bh = bid & 63, qc = bid >> 6;
    const int b = bh >> 2, h = bh & 3;
    const int q0 = qc * 128 + wave * 32;
    const size_t qk_off = ((size_t)b << 10) * 512 + h * 128;
    const ushortb* Qp = Qb + qk_off;
    const ushortb* Kp = Kb + qk_off;
    const ushortb* Vp = Vt + (((size_t)(b * 4 + h)) << 17);

    short8 qfA[4], qfB[4];   // B-frags: Q[q=l15 | 16+l15][k=quad*8+j]
    {
        const ushortb* qa = Qp + (size_t)(q0 + l15) * 512;
        const ushortb* qb = Qp + (size_t)(q0 + 16 + l15) * 512;
        #pragma unroll
        for (int kc = 0; kc < 4; ++kc) {
            qfA[kc] = *(const short8*)(qa + kc * 32 + quad * 8);
            qfB[kc] = *(const short8*)(qb + kc * 32 + quad * 8);
        }
    }

    f32x4 oA[8], oB[8];
    #pragma unroll
    for (int dt = 0; dt < 8; ++dt) {
        oA[dt] = (f32x4){0.f, 0.f, 0.f, 0.f};
        oB[dt] = (f32x4){0.f, 0.f, 0.f, 0.f};
    }
    float lA = 0.f, lB = 0.f;

    // initial stage -> buffer 0
    #pragma unroll
    for (int c = 0; c < 2; ++c) {
        int seg = wave * 2 + c;
        int rk = seg * 4 + (lane >> 4);
        int ck = (lane & 15) ^ (rk & 15);
        async_ld16(&sK[0][seg * 4][0], Kp + (size_t)rk * 512 + ck * 8);
        int dv = seg * 16 + (lane >> 2);
        int cv = (lane & 3) ^ (dv & 3);
        async_ld16(&sVt[0][seg * 16][0], Vp + ((size_t)dv << 10) + cv * 8);
    }

    int buf = 0;
    for (int t0 = 0; t0 < 1024; t0 += 32) {
        __syncthreads();   // DMA for 'buf' complete + prev compute done
        if (t0 + 32 < 1024) {
            int nb = buf ^ 1;
            #pragma unroll
            for (int c = 0; c < 2; ++c) {
                int seg = wave * 2 + c;
                int rk = seg * 4 + (lane >> 4);
                int ck = (lane & 15) ^ (rk & 15);
                async_ld16(&sK[nb][seg * 4][0], Kp + (size_t)(t0 + 32 + rk) * 512 + ck * 8);
                int dv = seg * 16 + (lane >> 2);
                int cv = (lane & 3) ^ (dv & 3);
                async_ld16(&sVt[nb][seg * 16][0], Vp + ((size_t)dv << 10) + t0 + 32 + cv * 8);
            }
        }

        // S^T: D[t][q]; t = quad*4+reg (+0/16), q = l15 (A-group) / 16+l15 (B)
        f32x4 sA0 = {0,0,0,0}, sA1 = {0,0,0,0}, sB0 = {0,0,0,0}, sB1 = {0,0,0,0};
        #pragma unroll
        for (int kc = 0; kc < 4; ++kc) {
            short8 k0f = *(const short8*)&sK[buf][l15][((kc * 4 + quad) ^ l15) * 8];
            short8 k1f = *(const short8*)&sK[buf][16 + l15][((kc * 4 + quad) ^ l15) * 8];
            sA0 = __builtin_amdgcn_mfma_f32_16x16x32_bf16(k0f, qfA[kc], sA0, 0, 0, 0);
            sA1 = __builtin_amdgcn_mfma_f32_16x16x32_bf16(k1f, qfA[kc], sA1, 0, 0, 0);
            sB0 = __builtin_amdgcn_mfma_f32_16x16x32_bf16(k0f, qfB[kc], sB0, 0, 0, 0);
            sB1 = __builtin_amdgcn_mfma_f32_16x16x32_bf16(k1f, qfB[kc], sB1, 0, 0, 0);
        }

        // fixed-max softmax: p = 2^score (log2e baked into Q scale)
        float pA0[4], pA1[4], pB0[4], pB1[4];
        float sumA = 0.f, sumB = 0.f;
        #pragma unroll
        for (int r = 0; r < 4; ++r) {
            pA0[r] = EXP2(sA0[r]); pA1[r] = EXP2(sA1[r]);
            pB0[r] = EXP2(sB0[r]); pB1[r] = EXP2(sB1[r]);
            sumA += pA0[r] + pA1[r];
            sumB += pB0[r] + pB1[r];
        }
        lA += sumA; lB += sumB;

        // store P[q][t] bf16 via packed converts (2 x uint2 per q-row half)
        uint2 w;
        w.x = pkbb(pA0[0], pA0[1]); w.y = pkbb(pA0[2], pA0[3]);
        *(uint2*)&sP[wave][l15][quad * 4] = w;
        w.x = pkbb(pA1[0], pA1[1]); w.y = pkbb(pA1[2], pA1[3]);
        *(uint2*)&sP[wave][l15][16 + quad * 4] = w;
        w.x = pkbb(pB0[0], pB0[1]); w.y = pkbb(pB0[2], pB0[3]);
        *(uint2*)&sP[wave][16 + l15][quad * 4] = w;
        w.x = pkbb(pB1[0], pB1[1]); w.y = pkbb(pB1[2], pB1[3]);
        *(uint2*)&sP[wave][16 + l15][16 + quad * 4] = w;

        short8 pfA = *(const short8*)&sP[wave][l15][quad * 8];
        short8 pfB = *(const short8*)&sP[wave][16 + l15][quad * 8];

        #pragma unroll
        for (int dt = 0; dt < 8; ++dt) {
            int d = dt * 16 + l15;
            short8 vfrag = *(const short8*)&sVt[buf][d][(quad ^ (d & 3)) * 8];
            oA[dt] = __builtin_amdgcn_mfma_f32_16x16x32_bf16(pfA, vfrag, oA[dt], 0, 0, 0);
            oB[dt] = __builtin_amdgcn_mfma_f32_16x16x32_bf16(pfB, vfrag, oB[dt], 0, 0, 0);
        }
        buf ^= 1;
    }

    lA += __shfl_xor(lA, 16); lA += __shfl_xor(lA, 32);
    lB += __shfl_xor(lB, 16); lB += __shfl_xor(lB, 32);

    const size_t obase = (((size_t)(b * 4 + h) << 10) + q0) << 7;
    #pragma unroll
    for (int r = 0; r < 4; ++r) {
        float invA = 1.0f / __shfl(lA, quad * 4 + r);
        float invB = 1.0f / __shfl(lB, quad * 4 + r);
        int qa = quad * 4 + r, qb = 16 + quad * 4 + r;
        #pragma unroll
        for (int dt = 0; dt < 8; ++dt) {
            O[obase + ((size_t)qa << 7) + dt * 16 + l15] = f2bb(oA[dt][r] * invA);
            O[obase + ((size_t)qb << 7) + dt * 16 + l15] = f2bb(oB[dt][r] * invB);
        }
    }
}

// ---------------------------------------------------------------------------
// LayerNorm over 512 features: wave per row, 8 elems/lane, shuffle reduce.
__global__ __launch_bounds__(256) void ln_kernel(const ushortb* __restrict__ in,
                                                 const float* __restrict__ g,
                                                 const float* __restrict__ bta,
                                                 ushortb* __restrict__ out)
{
    const int lane = threadIdx.x & 63, w = threadIdx.x >> 6;
    const size_t row = (size_t)blockIdx.x * 4 + w;
    const int e0 = lane * 8;
    short8 v8 = *(const short8*)(in + row * 512 + e0);
    float v[8];
    #pragma unroll
    for (int k = 0; k < 8; ++k) v[k] = bb2f((ushortb)((short*)&v8)[k]);
    float s = 0.f, sq = 0.f;
    #pragma unroll
    for (int k = 0; k < 8; ++k) { s += v[k]; sq += v[k] * v[k]; }
    #pragma unroll
    for (int o = 1; o < 64; o <<= 1) { s += __shfl_xor(s, o); sq += __shfl_xor(sq, o); }
    float mu = s * (1.0f / 512.0f);
    float var = sq * (1.0f / 512.0f) - mu * mu;
    float rstd = rsqrtf(var + 1e-5f);
    float4 g0 = *(const float4*)(g + e0),  g1 = *(const float4*)(g + e0 + 4);
    float4 b0 = *(const float4*)(bta + e0), b1 = *(const float4*)(bta + e0 + 4);
    float gg[8] = {g0.x, g0.y, g0.z, g0.w, g1.x, g1.y, g1.z, g1.w};
    float bb[8] = {b0.x, b0.y, b0.z, b0.w, b1.x, b1.y, b1.z, b1.w};
    short8 o8;
    #pragma unroll
    for (int k = 0; k < 8; ++k)
        ((short*)&o8)[k] = (short)f2bb((v[k] - mu) * rstd * gg[k] + bb[k]);
    *(short8*)(out + row * 512 + e0) = o8;
}

// ---------------------------------------------------------------------------
// MaxPool1d(16) + FC[32768,2] partial: grid (16 batch, 16 chunks), atomicAdd.
__global__ __launch_bounds__(256) void final_partial(const ushortb* __restrict__ ln2,
                                                     const float* __restrict__ fcw,
                                                     float* __restrict__ zbuf)
{
    const int b = blockIdx.x, chunk = blockIdx.y;
    const int tid = threadIdx.x;
    float a0 = 0.0f, a1 = 0.0f;
    #pragma unroll
    for (int t = 0; t < 8; ++t) {
        int m = chunk * 2048 + t * 256 + tid;
        int s = m >> 5, j = m & 31;
        const ushortb* p = ln2 + (((size_t)(b * 1024 + s)) << 9) + j * 16;
        float mx = -1e30f;
        #pragma unroll
        for (int e = 0; e < 16; ++e) mx = fmaxf(mx, bb2f(p[e]));
        a0 += mx * fcw[2 * m];
        a1 += mx * fcw[2 * m + 1];
    }
    __shared__ float r0[256], r1[256];
    r0[tid] = a0; r1[tid] = a1;
    __syncthreads();
    for (int o = 128; o > 0; o >>= 1) {
        if (tid < o) { r0[tid] += r0[tid + o]; r1[tid] += r1[tid + o]; }
        __syncthreads();
    }
    if (tid == 0) {
        atomicAdd(&zbuf[2 * b],     r0[0]);
        atomicAdd(&zbuf[2 * b + 1], r1[0]);
    }
}

__global__ __launch_bounds__(64) void final_logits(const float* __restrict__ zbuf,
                                                   const float* __restrict__ fcb,
                                                   float* __restrict__ out)
{
    int b = threadIdx.x;
    if (b < 16) {
        float z0 = zbuf[2 * b]     + fcb[0];
        float z1 = zbuf[2 * b + 1] + fcb[1];
        float mx = fmaxf(z0, z1);
        float lse = mx + logf(expf(z0 - mx) + expf(z1 - mx));
        out[2 * b]     = z0 - lse;
        out[2 * b + 1] = z1 - lse;
    }
}

// ---------------------------------------------------------------------------
extern "C" void kernel_launch(void* const* d_in, const int* in_sizes, int n_in,
                              void* d_out, int out_size, void* d_ws, size_t ws_size,
                              hipStream_t stream)
{
    const float* x     = (const float*)d_in[0];
    const float* emb_w = (const float*)d_in[1];
    const float* emb_b = (const float*)d_in[2];
    const float* WQ    = (const float*)d_in[3];
    const float* WK    = (const float*)d_in[4];
    const float* WV    = (const float*)d_in[5];
    const float* WO    = (const float*)d_in[6];
    const float* g1    = (const float*)d_in[7];
    const float* b1    = (const float*)d_in[8];
    const float* l1w   = (const float*)d_in[9];
    const float* l1b   = (const float*)d_in[10];
    const float* l2w   = (const float*)d_in[11];
    const float* l2b   = (const float*)d_in[12];
    const float* g2    = (const float*)d_in[13];
    const float* b2    = (const float*)d_in[14];
    const float* fcw   = (const float*)d_in[15];
    const float* fcb   = (const float*)d_in[16];
    float* out = (float*)d_out;

    char* ws = (char*)d_ws;
    const size_t Ub = (size_t)16384 * 512 * 2;   // 16.78 MB bf16 activation unit
    // u0: xb -> r1 -> r2   u1: h0b -> ln2   u2: Qb -> ln1
    // u3: Kb -> mid[0]     u4: Vt -> mid[1] u5: headR -> mid[2]  u6: mid[3]
    ushortb* xb    = (ushortb*)(ws + 0 * Ub);
    ushortb* h0b   = (ushortb*)(ws + 1 * Ub);
    ushortb* Qb    = (ushortb*)(ws + 2 * Ub);   // Kb = Qb + M*512, Vt = Qb + 2*M*512
    ushortb* Kb    = (ushortb*)(ws + 3 * Ub);
    ushortb* Vt    = (ushortb*)(ws + 4 * Ub);
    ushortb* headR = (ushortb*)(ws + 5 * Ub);
    ushortb* mid   = (ushortb*)(ws + 3 * Ub);   // [16384,2048] over u3..u6
    ushortb* r1    = xb;
    ushortb* ln1   = Qb;
    ushortb* r2    = xb;
    ushortb* ln2   = h0b;
    char* wb = ws + 7 * Ub;
    ushortb* embwt = (ushortb*)(wb);                        // [512][512]
    ushortb* wqkvt = (ushortb*)(wb + 524288);               // [1536][512]
    ushortb* wot   = (ushortb*)(wb + 2097152);              // [512][512]
    ushortb* l1wt  = (ushortb*)(wb + 2621440);              // [2048][512]
    ushortb* l2wt  = (ushortb*)(wb + 4718592);              // [512][2048]
    float*   pe    = (float*)  (wb + 6815744);              // [1024][512] fp32
    float*   zbuf  = (float*)  (wb + 8912896);              // [16][2]

    const int M = 16384;
    const float qscale = 0.12753139626997592f;  // log2(e)/sqrt(128)

    // prep
    conv_x<<<8192, 256, 0, stream>>>(x, xb);
    pe_kernel<<<2048, 256, 0, stream>>>(pe);
    pairT512<<<dim3(8, 8, 2), 256, 0, stream>>>(emb_w, WO, embwt, wot);
    qkvT<<<dim3(2, 8, 12), 256, 0, stream>>>(WQ, WK, WV, wqkvt, qscale);
    tileT<<<dim3(32, 8, 1), 256, 0, stream>>>(l1w, l1wt, 512, 2048, 1.0f);
    tileT<<<dim3(8, 32, 1), 256, 0, stream>>>(l2w, l2wt, 2048, 512, 1.0f);
    hipMemsetAsync(zbuf, 0, 16 * 2 * sizeof(float), stream);

    // 1) h0 = x @ emb_w + emb_b + pe
    gemm_mfma<EP_EMB><<<dim3(M / 128, 4), 256, 0, stream>>>(
        xb, embwt, emb_b, nullptr, pe, h0b, M, 512, 512);

    // 2) fused QKV projection (Q scale baked; V transposed in epilogue)
    gemm_mfma<EP_QKV><<<dim3(M / 128, 12), 256, 0, stream>>>(
        h0b, wqkvt, nullptr, nullptr, nullptr, Qb, M, 1536, 512);

    // 3) flash attention -> headR bf16 ([B,H,S,DK] flat == raw reshape)
    attn_mfma<<<512, 256, 0, stream>>>(Qb, Kb, Vt, headR);

    // 4) r1 = headR @ WO + h0 ; ln1 = LN(r1)
    gemm_mfma<EP_RES><<<dim3(M / 128, 4), 256, 0, stream>>>(
        headR, wot, nullptr, h0b, nullptr, r1, M, 512, 512);
    ln_kernel<<<M / 4, 256, 0, stream>>>(r1, g1, b1, ln1);

    // 5) FFN
    gemm_mfma<EP_BIAS_RELU><<<dim3(M / 128, 16), 256, 0, stream>>>(
        ln1, l1wt, l1b, nullptr, nullptr, mid, M, 2048, 512);
    gemm_mfma<EP_BIAS_RES><<<dim3(M / 128, 4), 256, 0, stream>>>(
        mid, l2wt, l2b, ln1, nullptr, r2, M, 512, 2048);
    ln_kernel<<<M / 4, 256, 0, stream>>>(r2, g2, b2, ln2);

    // 6) maxpool + FC + log_softmax
    final_partial<<<dim3(16, 16), 256, 0, stream>>>(ln2, fcw, zbuf);
    final_logits<<<1, 64, 0, stream>>>(zbuf, fcb, out);
}